// Round 3
// baseline (189.069 us; speedup 1.0000x reference)
//
#include <hip/hip_runtime.h>
#include <hip/hip_bf16.h>
#include <stdint.h>

// ModulatedConv2d: N=16, IC=OC=256, H=W=64, K=3, STYLE=512. fp32 in/out.
// out = demod[n,oc] * conv2d( x * (1+s)[n,ic], weight )   (StyleGAN2 identity)
// R7: deepen staging pipeline. R6's VM4-every-phase gave each half-tile only
//     2 phases of issue->wait slack (~800cyc < HBM ~900cyc; measured phase
//     1075cyc vs ~400 of real work). Now tile T stages B0',B1',A1' (of T+1)
//     at p0/p1/p2 and A0'' (of T+2) at p3 -> every half-tile gets 3-4 phases
//     of slack, waits become VM6 (3 half-tiles in flight, m201 discipline).
//     Uniform 36-iter loop: out-of-range prefetch offsets clamp to 0 (staged
//     into regions never read again; vmcnt accounting stays uniform).
//     Hazards: every stage-after-read gap >= 2 barriers (A0'' overwrites own
//     tile's A0, last read at p0, staged at p3); every read-after-stage
//     guarded by VM6 + following BAR (drain targets re-derived, see loop).

#define NB  16
#define IC  256
#define OC  256
#define HW  64
#define HWP 66
#define SD  512
#define SPATIAL 4096
#define HWPIC 16896   // HWP*IC

typedef __hip_bfloat16 bf16;
typedef __bf16 bf16x8 __attribute__((ext_vector_type(8)));
typedef float  f32x4  __attribute__((ext_vector_type(4)));
typedef uint32_t u32a3 __attribute__((address_space(3)));
typedef const uint32_t u32a1 __attribute__((address_space(1)));

static __device__ __forceinline__ unsigned short f2bu(float f) {
    bf16 h = __float2bfloat16(f);
    union { bf16 b; unsigned short u; } c; c.b = h; return c.u;
}
static __device__ __forceinline__ void gll16(const void* g, void* l) {
    __builtin_amdgcn_global_load_lds((u32a1*)g, (u32a3*)l, 16, 0, 0);
}

// --- P1: fused prep. blocks [0,256): wt2/wsq; [256,784): border; [784,1808): scale
__global__ __launch_bounds__(256)
void k_prep1(const float* __restrict__ weight, const float* __restrict__ style,
             const float* __restrict__ mod_w, const float* __restrict__ mod_b,
             float* __restrict__ wsq, bf16* __restrict__ wt2,
             uint4* __restrict__ xs4, float* __restrict__ scale) {
    int b = blockIdx.x, t = threadIdx.x;
    if (b < 256) {
        // wsq[oc,ic] = sum_r w^2 ; wt2[r][oc][ic] = bf16(w)
        int tid = b * 256 + t;
        const float* wp = weight + (size_t)tid * 9;
        float v[9], s = 0.f;
        #pragma unroll
        for (int r = 0; r < 9; ++r) { v[r] = wp[r]; s += v[r] * v[r]; }
        wsq[tid] = s;
        #pragma unroll
        for (int r = 0; r < 9; ++r) wt2[(r << 16) + tid] = __float2bfloat16(v[r]);
    } else if (b < 784) {
        // zero 1-px border ring of padded NHWC xs
        int idx = b - 256;
        int n = idx / 33, bx = idx - n * 33;
        int f = bx * 256 + t;
        int u = f >> 5, q = f & 31;
        if (u >= 260) return;
        int rb;
        if      (u <  66) rb = u;
        else if (u < 132) rb = 65 * 66 + (u - 66);
        else if (u < 196) rb = (u - 131) * 66;
        else              rb = (u - 195) * 66 + 65;
        xs4[(size_t)n * 139392 + rb * 32 + q] = make_uint4(0u, 0u, 0u, 0u);
    } else {
        // scale[n,ic] = 1 + style[n,:].mod_w[ic,:] + mod_b[ic]; one wave/output
        int lane = t & 63;
        int w = (b - 784) * 4 + (t >> 6);
        int n = w >> 8, ic = w & 255;
        const float4* mw4 = (const float4*)mod_w + (size_t)ic * 128 + lane * 2;
        const float4* st4 = (const float4*)style + (size_t)n * 128 + lane * 2;
        float4 a0 = mw4[0], a1 = mw4[1], s0 = st4[0], s1 = st4[1];
        float acc = a0.x*s0.x + a0.y*s0.y + a0.z*s0.z + a0.w*s0.w
                  + a1.x*s1.x + a1.y*s1.y + a1.z*s1.z + a1.w*s1.w;
        #pragma unroll
        for (int off = 32; off > 0; off >>= 1) acc += __shfl_down(acc, off);
        if (lane == 0) scale[w] = acc + mod_b[ic] + 1.0f;
    }
}

// --- P2: blocks [0,1024): xs modulate+transpose; [1024,1040): demod ---------
// Transpose tile swizzled: ushort index sp*256 + (ic ^ ((sp>>2&7)<<3)).
__global__ __launch_bounds__(256)
void k_prep2(const float* __restrict__ x, const float* __restrict__ scale,
             const float* __restrict__ wsq, bf16* __restrict__ xs,
             float* __restrict__ demod) {
    __shared__ unsigned short tile[HW * 256];   // 32 KB; reused by demod path
    int b = blockIdx.x, t = threadIdx.x;
    if (b < 1024) {
        int y = b & 63, n = b >> 6;
        const float* sc = scale + n * IC;
        const float4* xp4 = (const float4*)(x + ((size_t)n * IC) * SPATIAL + (size_t)y * HW);
        #pragma unroll
        for (int i = 0; i < 16; ++i) {
            int fid = i * 256 + t;
            int ic = fid >> 4, f4 = fid & 15;
            float4 v = xp4[(size_t)ic * 1024 + f4];
            float s = sc[ic];
            int sp = f4 << 2;
            int sw = ic ^ ((f4 & 7) << 3);      // (sp>>2)&7 == f4&7 for all 4 rows
            tile[(sp + 0) * 256 + sw] = f2bu(v.x * s);
            tile[(sp + 1) * 256 + sw] = f2bu(v.y * s);
            tile[(sp + 2) * 256 + sw] = f2bu(v.z * s);
            tile[(sp + 3) * 256 + sw] = f2bu(v.w * s);
        }
        __syncthreads();
        uint4* dst4 = (uint4*)(xs + (((size_t)n * HWP + (y + 1)) * HWP + 1) * IC);
        #pragma unroll
        for (int j = 0; j < 8; ++j) {
            int uid = j * 256 + t;
            int sp = uid >> 5, g = uid & 31;
            dst4[sp * 32 + g] =
                *(const uint4*)&tile[sp * 256 + ((g ^ ((sp >> 2) & 7)) << 3)];
        }
    } else {
        // demod[n,oc] = rsqrt( sum_ic wsq[oc,ic]*scale[n,ic]^2 + eps )
        int n = b - 1024, oc = t;
        float* sc = (float*)tile;
        sc[t] = scale[n * IC + t];
        __syncthreads();
        const float4* wp4 = (const float4*)(wsq + (size_t)oc * IC);
        const float4* sc4 = (const float4*)sc;
        float acc = 0.f;
        #pragma unroll 8
        for (int i = 0; i < 64; ++i) {
            float4 q = wp4[i], s = sc4[i];
            acc += q.x*s.x*s.x + q.y*s.y*s.y + q.z*s.z*s.z + q.w*s.w*s.w;
        }
        demod[n * OC + oc] = rsqrtf(acc + 1e-8f);
    }
}

// --- K9: implicit-GEMM conv, 256x256 tile, BK=64, 8 waves (2Mx4N), 8-phase,
// 1 barrier/phase, 3-half-tile-deep staging (VM6). LDS 128 KiB dynamic,
// XOR-seg swizzle conflict-free. Quadrants (A0,B0)(A0,B1)(A1,B1)(A1,B0).
#define VM6 asm volatile("s_waitcnt vmcnt(6)" ::: "memory")
#define BAR __builtin_amdgcn_s_barrier()

__global__ __launch_bounds__(512, 2)
void k_conv(const bf16* __restrict__ xs, const bf16* __restrict__ wt2,
            const float* __restrict__ demod, float* __restrict__ out) {
    extern __shared__ char smem[];              // 128 KiB
    int t = threadIdx.x, l = t & 63, w = t >> 6;
    int wm = w & 1, wn = w >> 1;
    int bid = blockIdx.x;
    int work = ((bid & 7) << 5) | (bid >> 3);   // XCD-contiguous: xcd*32 + slot
    int nimg = work >> 4;
    int ybase = (work & 15) << 2;               // 4 image rows per tile
    int spb = (work & 15) << 8;                 // 256 spatial positions

    // staging: half-tile = 128 rows x 64 k; wave w, lane l ->
    // row = w*8+(l>>3) (+64 for 2nd gll16), LDS seg l&7 holds global seg (l&7)^(l>>3).
    int srow = (w << 3) + (l >> 3);             // 0..63 (x coordinate)
    int gseg = (l & 7) ^ (l >> 3);
    const bf16* gA = xs + (((size_t)nimg * HWP + ybase) * HWP + srow) * IC + (gseg << 3);
    const bf16* gB = wt2 + ((size_t)srow << 8) + (gseg << 3);
    int stW = w << 10;                          // wave byte offset in half-tile

    // frag-read addressing (byte offsets; row stride 128 B)
    int aRow = ((wm << 6) + (l & 15)) << 7;
    int bRow = ((wn << 5) + (l & 15)) << 7;
    int sg0 = ((l >> 4) ^ (l & 7)) << 4;        // kk=0 swizzled seg
    int sg1 = sg0 ^ 64;                         // kk=1

    f32x4 acc[4][4][2];
    #pragma unroll
    for (int p = 0; p < 4; ++p)
        #pragma unroll
        for (int m = 0; m < 4; ++m)
            #pragma unroll
            for (int n = 0; n < 2; ++n) acc[p][m][n] = (f32x4){0.f, 0.f, 0.f, 0.f};

    bf16x8 af[4][2], bf0[2][2], bf1[2][2];

#define STG_A(ha, PARN, AOFF) do {                                          \
    const bf16* s_ = gA + (AOFF) + (ha) * 2 * HWPIC;                        \
    char* d_ = smem + (PARN) * 32768 + (ha) * 16384 + stW;                  \
    gll16(s_, d_); gll16(s_ + HWPIC, d_ + 8192); } while (0)
#define STG_B(hb, PARN, BOFF) do {                                          \
    const bf16* s_ = gB + (BOFF) + (hb) * (128 * IC);                       \
    char* d_ = smem + 65536 + (PARN) * 32768 + (hb) * 16384 + stW;          \
    gll16(s_, d_); gll16(s_ + 64 * IC, d_ + 8192); } while (0)
#define LD_A(QA) do { const char* Ab_ = Ap + (QA) * 16384 + aRow;           \
    _Pragma("unroll") for (int m_ = 0; m_ < 4; ++m_) {                      \
        af[m_][0] = *(const bf16x8*)(Ab_ + m_ * 2048 + sg0);                \
        af[m_][1] = *(const bf16x8*)(Ab_ + m_ * 2048 + sg1); } } while (0)
#define LD_B(DST, QB) do { const char* Bb_ = Bp + (QB) * 16384 + bRow;      \
    _Pragma("unroll") for (int n_ = 0; n_ < 2; ++n_) {                      \
        DST[n_][0] = *(const bf16x8*)(Bb_ + n_ * 2048 + sg0);               \
        DST[n_][1] = *(const bf16x8*)(Bb_ + n_ * 2048 + sg1); } } while (0)
#define MM(P, BF) do {                                                      \
    __builtin_amdgcn_s_setprio(1);                                          \
    _Pragma("unroll") for (int kk_ = 0; kk_ < 2; ++kk_)                     \
    _Pragma("unroll") for (int m_ = 0; m_ < 4; ++m_)                        \
    _Pragma("unroll") for (int n_ = 0; n_ < 2; ++n_)                        \
        acc[P][m_][n_] = __builtin_amdgcn_mfma_f32_16x16x32_bf16(           \
            af[m_][kk_], BF[n_][kk_], acc[P][m_][n_], 0, 0, 0);             \
    __builtin_amdgcn_s_setprio(0); } while (0)

    // prologue: stage A0,B0,B1,A1 of T0 + A0 of T1 (r=0, ic=64).
    // VM6 drains exactly A0(T0)+B0(T0) (10 issued - 6).
    STG_A(0, 0, 0);
    STG_B(0, 0, 0);
    STG_B(1, 0, 0);
    STG_A(1, 0, 0);
    STG_A(0, 1, 64);
    VM6;
    BAR;

    #pragma clang loop unroll(disable)
    for (int T = 0; T < 36; ++T) {
        int par = T & 1, parn = par ^ 1;
        const char* Ap = smem + par * 32768;
        const char* Bp = smem + 65536 + par * 32768;
        int T1 = T + 1, T2 = T + 2;
        int r1 = T1 >> 2, ic1 = (T1 & 3) << 6;
        int ky1 = r1 / 3, kx1 = r1 - ky1 * 3;
        int aoff1 = T1 < 36 ? (ky1 * HWP + kx1) * IC + ic1 : 0;   // clamp: garbage
        int boff1 = T1 < 36 ? (r1 << 16) + ic1 : 0;               // never read
        int r2 = T2 >> 2, ic2 = (T2 & 3) << 6;
        int ky2 = r2 / 3, kx2 = r2 - ky2 * 3;
        int aoff2 = T2 < 36 ? (ky2 * HWP + kx2) * IC + ic2 : 0;

        // p0: (A0,B0). A0 staged T-1.p3, B0 staged T.p0... of prev tile:
        // VM6 here drains through B1(T) [staged T-1.p1] for p1's reads.
        LD_A(0); LD_B(bf0, 0);
        STG_B(0, parn, boff1);                  // B0 of T+1
        VM6; BAR; MM(0, bf0);
        // p1: (A0,B1), af reused. VM6 drains through A1(T) for p2's reads.
        LD_B(bf1, 1);
        STG_B(1, parn, boff1);                  // B1 of T+1
        VM6; BAR; MM(1, bf1);
        // p2: (A1,B1), bf1 reused. no wait.
        LD_A(1);
        STG_A(1, parn, aoff1);                  // A1 of T+1
        BAR; MM(2, bf1);
        // p3: (A1,B0), regs only. A0'' overwrites own A0 (last read p0,
        // 3 barriers back). VM6 drains through A0(T+1)+B0(T+1) for T+1.p0.
        STG_A(0, par, aoff2);                   // A0 of T+2
        VM6; BAR; MM(3, bf0);
    }
    // no tail: T>=36 prefetches were clamped garbage into dead regions;
    // compiler drains vmcnt before endpgm (overlaps epilogue stores).

    // epilogue: D[row=(l>>4)*4+v][col=l&15]; 16B stores along spatial
    const float* dm = demod + nimg * OC;
    int ocol = l & 15, orow = (l >> 4) << 2;
    #pragma unroll
    for (int p = 0; p < 4; ++p) {
        int qa = p >> 1, qb = qa ^ (p & 1);     // (0,0)(0,1)(1,1)(1,0)
        #pragma unroll
        for (int n = 0; n < 2; ++n) {
            int oc = (qb << 7) + (wn << 5) + (n << 4) + ocol;
            float d = dm[oc];
            size_t ob = ((size_t)(nimg * OC + oc)) * SPATIAL
                      + spb + (qa << 7) + (wm << 6) + orow;
            #pragma unroll
            for (int m = 0; m < 4; ++m) {
                f32x4 a = acc[p][m][n];
                f32x4 o = { a[0] * d, a[1] * d, a[2] * d, a[3] * d };
                *reinterpret_cast<f32x4*>(out + ob + m * 16) = o;
            }
        }
    }
}

extern "C" void kernel_launch(void* const* d_in, const int* in_sizes, int n_in,
                              void* d_out, int out_size, void* d_ws, size_t ws_size,
                              hipStream_t stream) {
    const float* x      = (const float*)d_in[0];
    const float* style  = (const float*)d_in[1];
    const float* weight = (const float*)d_in[2];
    const float* mod_w  = (const float*)d_in[3];
    const float* mod_b  = (const float*)d_in[4];
    float* out = (float*)d_out;

    char* ws = (char*)d_ws;                  // ~37.2 MB
    float* scale = (float*)(ws + 0);         // 16 KB
    float* demod = (float*)(ws + 16384);     // 16 KB
    float* wsq   = (float*)(ws + 32768);     // 256 KB
    bf16*  wt2   = (bf16*)(ws + 294912);     // 1.18 MB [r][oc][ic]
    bf16*  xs    = (bf16*)(ws + 1474560);    // 35.7 MB padded NHWC

    static int s_attr = 0;
    if (!s_attr) {
        hipFuncSetAttribute(reinterpret_cast<const void*>(k_conv),
                            hipFuncAttributeMaxDynamicSharedMemorySize, 131072);
        s_attr = 1;
    }

    k_prep1<<<1808, 256, 0, stream>>>(weight, style, mod_w, mod_b,
                                      wsq, wt2, (uint4*)xs, scale);
    k_prep2<<<1040, 256, 0, stream>>>(x, scale, wsq, xs, demod);
    k_conv<<<256, 512, 131072, stream>>>(xs, wt2, demod, out);
}

// Round 4
// 188.686 us; speedup vs baseline: 1.0020x; 1.0020x over previous
//
#include <hip/hip_runtime.h>
#include <hip/hip_bf16.h>
#include <stdint.h>

// ModulatedConv2d: N=16, IC=OC=256, H=W=64, K=3, STYLE=512. fp32 in/out.
// out = demod[n,oc] * conv2d( x * (1+s)[n,ic], weight )   (StyleGAN2 identity)
// R8: revert R7 (deeper vmem slack regressed: latency wasn't the stall) to the
//     R6 skeleton, and add ONE-PHASE REGISTER READ-AHEAD: every ds_read issues
//     the phase BEFORE its MM consumes it (p0: bf1<-B1; p1: afB<-A1; p3:
//     afA<-A0', bf0N<-B0'), so no MFMA waits on the shared post-barrier LDS
//     queue. A-frags use two role-fixed buffers (afA=A0, afB=A1); bf0
//     ping-pongs by tile parity (2-tile-unrolled loop -> static indexing).
//     Staging order / VM4 placements / barriers identical to R6 (drain
//     walk-through: B1 readable post p0-VM4, A1 post p1-VM4, A0'/B0' post
//     p3-VM4; write-after-read gaps grew vs R6 since prefetch moves last
//     reads earlier).

#define NB  16
#define IC  256
#define OC  256
#define HW  64
#define HWP 66
#define SD  512
#define SPATIAL 4096
#define HWPIC 16896   // HWP*IC

typedef __hip_bfloat16 bf16;
typedef __bf16 bf16x8 __attribute__((ext_vector_type(8)));
typedef float  f32x4  __attribute__((ext_vector_type(4)));
typedef uint32_t u32a3 __attribute__((address_space(3)));
typedef const uint32_t u32a1 __attribute__((address_space(1)));

static __device__ __forceinline__ unsigned short f2bu(float f) {
    bf16 h = __float2bfloat16(f);
    union { bf16 b; unsigned short u; } c; c.b = h; return c.u;
}
static __device__ __forceinline__ void gll16(const void* g, void* l) {
    __builtin_amdgcn_global_load_lds((u32a1*)g, (u32a3*)l, 16, 0, 0);
}

// --- P1: fused prep. blocks [0,256): wt2/wsq; [256,784): border; [784,1808): scale
__global__ __launch_bounds__(256)
void k_prep1(const float* __restrict__ weight, const float* __restrict__ style,
             const float* __restrict__ mod_w, const float* __restrict__ mod_b,
             float* __restrict__ wsq, bf16* __restrict__ wt2,
             uint4* __restrict__ xs4, float* __restrict__ scale) {
    int b = blockIdx.x, t = threadIdx.x;
    if (b < 256) {
        int tid = b * 256 + t;
        const float* wp = weight + (size_t)tid * 9;
        float v[9], s = 0.f;
        #pragma unroll
        for (int r = 0; r < 9; ++r) { v[r] = wp[r]; s += v[r] * v[r]; }
        wsq[tid] = s;
        #pragma unroll
        for (int r = 0; r < 9; ++r) wt2[(r << 16) + tid] = __float2bfloat16(v[r]);
    } else if (b < 784) {
        int idx = b - 256;
        int n = idx / 33, bx = idx - n * 33;
        int f = bx * 256 + t;
        int u = f >> 5, q = f & 31;
        if (u >= 260) return;
        int rb;
        if      (u <  66) rb = u;
        else if (u < 132) rb = 65 * 66 + (u - 66);
        else if (u < 196) rb = (u - 131) * 66;
        else              rb = (u - 195) * 66 + 65;
        xs4[(size_t)n * 139392 + rb * 32 + q] = make_uint4(0u, 0u, 0u, 0u);
    } else {
        int lane = t & 63;
        int w = (b - 784) * 4 + (t >> 6);
        int n = w >> 8, ic = w & 255;
        const float4* mw4 = (const float4*)mod_w + (size_t)ic * 128 + lane * 2;
        const float4* st4 = (const float4*)style + (size_t)n * 128 + lane * 2;
        float4 a0 = mw4[0], a1 = mw4[1], s0 = st4[0], s1 = st4[1];
        float acc = a0.x*s0.x + a0.y*s0.y + a0.z*s0.z + a0.w*s0.w
                  + a1.x*s1.x + a1.y*s1.y + a1.z*s1.z + a1.w*s1.w;
        #pragma unroll
        for (int off = 32; off > 0; off >>= 1) acc += __shfl_down(acc, off);
        if (lane == 0) scale[w] = acc + mod_b[ic] + 1.0f;
    }
}

// --- P2: blocks [0,1024): xs modulate+transpose; [1024,1040): demod ---------
__global__ __launch_bounds__(256)
void k_prep2(const float* __restrict__ x, const float* __restrict__ scale,
             const float* __restrict__ wsq, bf16* __restrict__ xs,
             float* __restrict__ demod) {
    __shared__ unsigned short tile[HW * 256];   // 32 KB; reused by demod path
    int b = blockIdx.x, t = threadIdx.x;
    if (b < 1024) {
        int y = b & 63, n = b >> 6;
        const float* sc = scale + n * IC;
        const float4* xp4 = (const float4*)(x + ((size_t)n * IC) * SPATIAL + (size_t)y * HW);
        #pragma unroll
        for (int i = 0; i < 16; ++i) {
            int fid = i * 256 + t;
            int ic = fid >> 4, f4 = fid & 15;
            float4 v = xp4[(size_t)ic * 1024 + f4];
            float s = sc[ic];
            int sp = f4 << 2;
            int sw = ic ^ ((f4 & 7) << 3);
            tile[(sp + 0) * 256 + sw] = f2bu(v.x * s);
            tile[(sp + 1) * 256 + sw] = f2bu(v.y * s);
            tile[(sp + 2) * 256 + sw] = f2bu(v.z * s);
            tile[(sp + 3) * 256 + sw] = f2bu(v.w * s);
        }
        __syncthreads();
        uint4* dst4 = (uint4*)(xs + (((size_t)n * HWP + (y + 1)) * HWP + 1) * IC);
        #pragma unroll
        for (int j = 0; j < 8; ++j) {
            int uid = j * 256 + t;
            int sp = uid >> 5, g = uid & 31;
            dst4[sp * 32 + g] =
                *(const uint4*)&tile[sp * 256 + ((g ^ ((sp >> 2) & 7)) << 3)];
        }
    } else {
        int n = b - 1024, oc = t;
        float* sc = (float*)tile;
        sc[t] = scale[n * IC + t];
        __syncthreads();
        const float4* wp4 = (const float4*)(wsq + (size_t)oc * IC);
        const float4* sc4 = (const float4*)sc;
        float acc = 0.f;
        #pragma unroll 8
        for (int i = 0; i < 64; ++i) {
            float4 q = wp4[i], s = sc4[i];
            acc += q.x*s.x*s.x + q.y*s.y*s.y + q.z*s.z*s.z + q.w*s.w*s.w;
        }
        demod[n * OC + oc] = rsqrtf(acc + 1e-8f);
    }
}

// --- K10: implicit-GEMM conv, 256x256 tile, BK=64, 8 waves (2Mx4N), 8-phase,
// 1 barrier/phase, register read-ahead. LDS 128 KiB dynamic, XOR-seg swizzle.
// Quadrants (A0,B0)(A0,B1)(A1,B1)(A1,B0); tile T stages T+1's A0,B0,B1,A1 at
// p0..p3 into the other parity; VM4 at p0/p1/p3 (never 0 in main loop).
#define VM4 asm volatile("s_waitcnt vmcnt(4)" ::: "memory")
#define VM2 asm volatile("s_waitcnt vmcnt(2)" ::: "memory")
#define VM0 asm volatile("s_waitcnt vmcnt(0)" ::: "memory")
#define BAR __builtin_amdgcn_s_barrier()
#define SB0 __builtin_amdgcn_sched_barrier(0)

__global__ __launch_bounds__(512, 2)
void k_conv(const bf16* __restrict__ xs, const bf16* __restrict__ wt2,
            const float* __restrict__ demod, float* __restrict__ out) {
    extern __shared__ char smem[];              // 128 KiB
    int t = threadIdx.x, l = t & 63, w = t >> 6;
    int wm = w & 1, wn = w >> 1;
    int bid = blockIdx.x;
    int work = ((bid & 7) << 5) | (bid >> 3);   // XCD-contiguous: xcd*32 + slot
    int nimg = work >> 4;
    int ybase = (work & 15) << 2;               // 4 image rows per tile
    int spb = (work & 15) << 8;                 // 256 spatial positions

    // staging: half-tile = 128 rows x 64 k; wave w, lane l ->
    // row = w*8+(l>>3) (+64 for 2nd gll16), LDS seg l&7 holds global seg (l&7)^(l>>3).
    int srow = (w << 3) + (l >> 3);
    int gseg = (l & 7) ^ (l >> 3);
    const bf16* gA = xs + (((size_t)nimg * HWP + ybase) * HWP + srow) * IC + (gseg << 3);
    const bf16* gB = wt2 + ((size_t)srow << 8) + (gseg << 3);
    int stW = w << 10;                          // wave byte offset in half-tile

    // frag-read addressing (byte offsets; row stride 128 B)
    int aRow = ((wm << 6) + (l & 15)) << 7;
    int bRow = ((wn << 5) + (l & 15)) << 7;
    int sg0 = ((l >> 4) ^ (l & 7)) << 4;        // kk=0 swizzled seg
    int sg1 = sg0 ^ 64;                         // kk=1

    f32x4 acc[4][4][2];
    #pragma unroll
    for (int p = 0; p < 4; ++p)
        #pragma unroll
        for (int m = 0; m < 4; ++m)
            #pragma unroll
            for (int n = 0; n < 2; ++n) acc[p][m][n] = (f32x4){0.f, 0.f, 0.f, 0.f};

    // role-fixed frag buffers: afA holds A0, afB holds A1; bf0A/bf0B ping-pong
    // by tile parity (static names, never runtime-indexed -> no scratch).
    bf16x8 afA[4][2], afB[4][2], bf0A[2][2], bf0B[2][2], bf1[2][2];

#define STG_A(ha, PARN, AOFF) do {                                          \
    const bf16* s_ = gA + (AOFF) + (ha) * 2 * HWPIC;                        \
    char* d_ = smem + (PARN) * 32768 + (ha) * 16384 + stW;                  \
    gll16(s_, d_); gll16(s_ + HWPIC, d_ + 8192); } while (0)
#define STG_B(hb, PARN, BOFF) do {                                          \
    const bf16* s_ = gB + (BOFF) + (hb) * (128 * IC);                       \
    char* d_ = smem + 65536 + (PARN) * 32768 + (hb) * 16384 + stW;          \
    gll16(s_, d_); gll16(s_ + 64 * IC, d_ + 8192); } while (0)
#define RD_A(DST, BASE) do { const char* A_ = (const char*)(BASE);          \
    _Pragma("unroll") for (int m_ = 0; m_ < 4; ++m_) {                      \
        DST[m_][0] = *(const bf16x8*)(A_ + m_ * 2048 + sg0);                \
        DST[m_][1] = *(const bf16x8*)(A_ + m_ * 2048 + sg1); } } while (0)
#define RD_B(DST, BASE) do { const char* B_ = (const char*)(BASE);          \
    _Pragma("unroll") for (int n_ = 0; n_ < 2; ++n_) {                      \
        DST[n_][0] = *(const bf16x8*)(B_ + n_ * 2048 + sg0);                \
        DST[n_][1] = *(const bf16x8*)(B_ + n_ * 2048 + sg1); } } while (0)
#define MM(P, AF, BF) do {                                                  \
    __builtin_amdgcn_s_setprio(1);                                          \
    _Pragma("unroll") for (int kk_ = 0; kk_ < 2; ++kk_)                     \
    _Pragma("unroll") for (int m_ = 0; m_ < 4; ++m_)                        \
    _Pragma("unroll") for (int n_ = 0; n_ < 2; ++n_)                        \
        acc[P][m_][n_] = __builtin_amdgcn_mfma_f32_16x16x32_bf16(           \
            AF[m_][kk_], BF[n_][kk_], acc[P][m_][n_], 0, 0, 0);             \
    __builtin_amdgcn_s_setprio(0); } while (0)

// One tile: reads one phase ahead of use. Staging/VM/BAR structure == R6.
#define TILE(PAR, BF0C, BF0N, AOFF1, BOFF1) do {                            \
    const char* Ap_  = smem + (PAR) * 32768;                                \
    const char* Bp_  = smem + 65536 + (PAR) * 32768;                        \
    const char* Apn_ = smem + ((PAR) ^ 1) * 32768;                          \
    const char* Bpn_ = smem + 65536 + ((PAR) ^ 1) * 32768;                  \
    /* p0: MM(A0,B0) on prefetched regs; prefetch bf1<-B1 (drained here) */ \
    STG_A(0, (PAR) ^ 1, AOFF1);                                             \
    VM4; BAR;                                                               \
    RD_B(bf1, Bp_ + 16384 + bRow);                                          \
    SB0;                                                                    \
    MM(0, afA, BF0C);                                                       \
    /* p1: MM(A0,B1); prefetch afB<-A1 (drained here) */                    \
    STG_B(0, (PAR) ^ 1, BOFF1);                                             \
    VM4; BAR;                                                               \
    RD_A(afB, Ap_ + 16384 + aRow);                                          \
    SB0;                                                                    \
    MM(1, afA, bf1);                                                        \
    /* p2: MM(A1,B1); no reads */                                           \
    STG_B(1, (PAR) ^ 1, BOFF1);                                             \
    BAR;                                                                    \
    MM(2, afB, bf1);                                                        \
    /* p3: MM(A1,B0); prefetch afA<-A0', BF0N<-B0' (drained here) */        \
    STG_A(1, (PAR) ^ 1, AOFF1);                                             \
    VM4; BAR;                                                               \
    RD_A(afA, Apn_ + aRow);                                                 \
    RD_B(BF0N, Bpn_ + bRow);                                                \
    SB0;                                                                    \
    MM(3, afB, BF0C);                                                       \
} while (0)

    // prologue: stage tile 0 (A0,B0,B1,A1); VM4 drains A0,B0; prefetch them.
    STG_A(0, 0, 0);
    STG_B(0, 0, 0);
    STG_B(1, 0, 0);
    STG_A(1, 0, 0);
    VM4;
    BAR;
    RD_A(afA, smem + aRow);
    RD_B(bf0A, smem + 65536 + bRow);

    #pragma clang loop unroll(disable)
    for (int TT = 0; TT < 17; ++TT) {
        int Tn1 = 2 * TT + 1, Tn2 = 2 * TT + 2;
        int r1 = Tn1 >> 2, ic1 = (Tn1 & 3) << 6;
        int ky1 = r1 / 3, kx1 = r1 - ky1 * 3;
        int aoff1 = (ky1 * HWP + kx1) * IC + ic1, boff1 = (r1 << 16) + ic1;
        int r2 = Tn2 >> 2, ic2 = (Tn2 & 3) << 6;
        int ky2 = r2 / 3, kx2 = r2 - ky2 * 3;
        int aoff2 = (ky2 * HWP + kx2) * IC + ic2, boff2 = (r2 << 16) + ic2;
        TILE(0, bf0A, bf0B, aoff1, boff1);      // even tile, cur bf0A
        TILE(1, bf0B, bf0A, aoff2, boff2);      // odd tile, cur bf0B
    }
    {   // tile 34 (par 0): stages tile 35 (r=8, ic=192)
        int aoff35 = (2 * HWP + 2) * IC + 192, boff35 = (8 << 16) + 192;
        TILE(0, bf0A, bf0B, aoff35, boff35);
    }
    {   // tile 35 tail (par 1, cur bf0B): no staging; drains 2->0, reads ahead
        const char* Ap_ = smem + 32768;
        const char* Bp_ = smem + 65536 + 32768;
        VM2; BAR;
        RD_B(bf1, Bp_ + 16384 + bRow);
        SB0;
        MM(0, afA, bf0B);
        VM0; BAR;
        RD_A(afB, Ap_ + 16384 + aRow);
        SB0;
        MM(1, afA, bf1);
        MM(2, afB, bf1);
        MM(3, afB, bf0B);
    }

    // epilogue: D[row=(l>>4)*4+v][col=l&15]; 16B stores along spatial
    const float* dm = demod + nimg * OC;
    int ocol = l & 15, orow = (l >> 4) << 2;
    #pragma unroll
    for (int p = 0; p < 4; ++p) {
        int qa = p >> 1, qb = qa ^ (p & 1);     // (0,0)(0,1)(1,1)(1,0)
        #pragma unroll
        for (int n = 0; n < 2; ++n) {
            int oc = (qb << 7) + (wn << 5) + (n << 4) + ocol;
            float d = dm[oc];
            size_t ob = ((size_t)(nimg * OC + oc)) * SPATIAL
                      + spb + (qa << 7) + (wm << 6) + orow;
            #pragma unroll
            for (int m = 0; m < 4; ++m) {
                f32x4 a = acc[p][m][n];
                f32x4 o = { a[0] * d, a[1] * d, a[2] * d, a[3] * d };
                *reinterpret_cast<f32x4*>(out + ob + m * 16) = o;
            }
        }
    }
}

extern "C" void kernel_launch(void* const* d_in, const int* in_sizes, int n_in,
                              void* d_out, int out_size, void* d_ws, size_t ws_size,
                              hipStream_t stream) {
    const float* x      = (const float*)d_in[0];
    const float* style  = (const float*)d_in[1];
    const float* weight = (const float*)d_in[2];
    const float* mod_w  = (const float*)d_in[3];
    const float* mod_b  = (const float*)d_in[4];
    float* out = (float*)d_out;

    char* ws = (char*)d_ws;                  // ~37.2 MB
    float* scale = (float*)(ws + 0);         // 16 KB
    float* demod = (float*)(ws + 16384);     // 16 KB
    float* wsq   = (float*)(ws + 32768);     // 256 KB
    bf16*  wt2   = (bf16*)(ws + 294912);     // 1.18 MB [r][oc][ic]
    bf16*  xs    = (bf16*)(ws + 1474560);    // 35.7 MB padded NHWC

    static int s_attr = 0;
    if (!s_attr) {
        hipFuncSetAttribute(reinterpret_cast<const void*>(k_conv),
                            hipFuncAttributeMaxDynamicSharedMemorySize, 131072);
        s_attr = 1;
    }

    k_prep1<<<1808, 256, 0, stream>>>(weight, style, mod_w, mod_b,
                                      wsq, wt2, (uint4*)xs, scale);
    k_prep2<<<1040, 256, 0, stream>>>(x, scale, wsq, xs, demod);
    k_conv<<<256, 512, 131072, stream>>>(xs, wt2, demod, out);
}